// Round 2
// baseline (862.738 us; speedup 1.0000x reference)
//
#include <hip/hip_runtime.h>
#include <cstdint>
#include <cstddef>

#define LOG2E 1.44269504088896340736f
#define LN2   0.69314718055994530942f

// Fast transcendental wrappers -> single gfx950 instructions.
__device__ __forceinline__ float fast_log2(float x) { return __builtin_amdgcn_logf(x); }   // v_log_f32
__device__ __forceinline__ float fast_exp2(float x) { return __builtin_amdgcn_exp2f(x); }  // v_exp_f32
__device__ __forceinline__ float fast_rcp(float x)  { return __builtin_amdgcn_rcpf(x); }   // v_rcp_f32

// B=4096, D_IN=784, D_Z=128, N_TRIALS=256, T_TEMP=1.0

// ---------------------------------------------------------------------------
// K1: encoder GEMM  du = min(x @ W_enc + b_enc, 5)   (unchanged from R0)
// ---------------------------------------------------------------------------
__global__ __launch_bounds__(256) void enc_kernel(const float* __restrict__ x,
                                                  const float* __restrict__ W,
                                                  const float* __restrict__ bias,
                                                  float* __restrict__ du) {
  __shared__ float xs[16][16];
  __shared__ float ws[16][128];
  const int tid  = threadIdx.x;
  const int row0 = blockIdx.x * 16;
  const int cg   = tid & 31;
  const int rg   = tid >> 5;

  float4 a0 = {0.f, 0.f, 0.f, 0.f};
  float4 a1 = {0.f, 0.f, 0.f, 0.f};

  for (int k0 = 0; k0 < 784; k0 += 16) {
    __syncthreads();
    if (tid < 64) {
      int r = tid >> 2, kc = (tid & 3) * 4;
      *(float4*)&xs[r][kc] = *(const float4*)&x[(size_t)(row0 + r) * 784 + k0 + kc];
    }
#pragma unroll
    for (int j = 0; j < 2; j++) {
      int i = tid + 256 * j;
      int k = i >> 5, c4 = (i & 31) * 4;
      *(float4*)&ws[k][c4] = *(const float4*)&W[(size_t)(k0 + k) * 128 + c4];
    }
    __syncthreads();
#pragma unroll
    for (int k = 0; k < 16; k++) {
      float x0 = xs[rg * 2][k];
      float x1 = xs[rg * 2 + 1][k];
      float4 w = *(const float4*)&ws[k][cg * 4];
      a0.x = fmaf(x0, w.x, a0.x); a0.y = fmaf(x0, w.y, a0.y);
      a0.z = fmaf(x0, w.z, a0.z); a0.w = fmaf(x0, w.w, a0.w);
      a1.x = fmaf(x1, w.x, a1.x); a1.y = fmaf(x1, w.y, a1.y);
      a1.z = fmaf(x1, w.z, a1.z); a1.w = fmaf(x1, w.w, a1.w);
    }
  }

  float4 bb = *(const float4*)&bias[cg * 4];
  float4 r0, r1;
  r0.x = fminf(a0.x + bb.x, 5.f); r0.y = fminf(a0.y + bb.y, 5.f);
  r0.z = fminf(a0.z + bb.z, 5.f); r0.w = fminf(a0.w + bb.w, 5.f);
  r1.x = fminf(a1.x + bb.x, 5.f); r1.y = fminf(a1.y + bb.y, 5.f);
  r1.z = fminf(a1.z + bb.z, 5.f); r1.w = fminf(a1.w + bb.w, 5.f);
  *(float4*)&du[(size_t)(row0 + rg * 2)     * 128 + cg * 4] = r0;
  *(float4*)&du[(size_t)(row0 + rg * 2 + 1) * 128 + cg * 4] = r1;
}

// ---------------------------------------------------------------------------
// K2: exponential race — reverted to the R0 version (known-good, part of the
//   788 us config). 4 chains/thread, float4 loads, per-lane predication,
//   wave-uniform ballot exit. R1's 2-chain variant doubled wave count with
//   iteration count pinned by slowest chain/row -> 2x loop+VMEM overhead.
// ---------------------------------------------------------------------------
__global__ __launch_bounds__(256) void race_kernel(const float* __restrict__ u,
                                                   const float* __restrict__ du,
                                                   const float* __restrict__ prior,
                                                   float* __restrict__ zout) {
  const int g  = blockIdx.x * 256 + threadIdx.x;  // 0..131071
  const int b  = g >> 5;                          // batch row (32 threads/row)
  const int z4 = (g & 31) * 4;                    // z-quad start

  const float4 d = *(const float4*)&du[(size_t)b * 128 + z4];
  const float4 p = *(const float4*)&prior[z4];

  float sinv[4];
  {
    const float dd[4] = {d.x, d.y, d.z, d.w};
    const float pp[4] = {p.x, p.y, p.z, p.w};
#pragma unroll
    for (int j = 0; j < 4; j++) {
      float lr   = fminf(dd[j] + fminf(pp[j], 5.f), 5.f);
      float rate = fast_exp2(lr * LOG2E) + 1e-6f;   // e^lr
      sinv[j]    = -LN2 / rate;                     // folds ln2 and 1/rate
    }
  }

  float t[4]   = {0.f, 0.f, 0.f, 0.f};
  float acc[4] = {0.f, 0.f, 0.f, 0.f};
  const float* up = u + (size_t)b * 128 + z4;
  const float TMAX = 18.f;

  for (int tt = 0; tt < 256; tt += 2) {
    // monotone: once all 4 chains pass TMAX this lane is done forever
    bool act = fminf(fminf(t[0], t[1]), fminf(t[2], t[3])) < TMAX;
    if (!__any(act)) break;          // wave-uniform exit
    if (act) {
      float4 ua = *(const float4*)&up[(size_t)tt * (4096 * 128)];
      float4 ub = *(const float4*)&up[(size_t)(tt + 1) * (4096 * 128)];
      const float uaj[4] = {ua.x, ua.y, ua.z, ua.w};
      const float ubj[4] = {ub.x, ub.y, ub.z, ub.w};
#pragma unroll
      for (int j = 0; j < 4; j++) {
        float l = fast_log2(1.f - uaj[j]);          // -log1p(-u) = -ln2*log2(1-u)
        t[j] = fmaf(l, sinv[j], t[j]);
        float e = fast_exp2(fmaf(t[j], LOG2E, -LOG2E));
        acc[j] += fast_rcp(1.f + e);                // sigmoid(1 - times)
        l = fast_log2(1.f - ubj[j]);
        t[j] = fmaf(l, sinv[j], t[j]);
        e = fast_exp2(fmaf(t[j], LOG2E, -LOG2E));
        acc[j] += fast_rcp(1.f + e);
      }
    }
  }

  float4 r; r.x = acc[0]; r.y = acc[1]; r.z = acc[2]; r.w = acc[3];
  *(float4*)&zout[(size_t)b * 128 + z4] = r;
}

// ---------------------------------------------------------------------------
// K3: decoder  y = sigmoid(z @ W_dec + b_dec), v2 (kept from R1).
//   No LDS. Register-block 4 cols x 8 rows per thread (32 accs);
//   z read with block-uniform addresses straight from global (scalarizes
//   to s_load / cache broadcast). W reads coalesced, L2-resident (401 KB).
//   k-accumulation order identical to v1 -> bit-identical y.
// ---------------------------------------------------------------------------
__global__ __launch_bounds__(256) void dec_kernel(const float* __restrict__ z,
                                                  const float* __restrict__ W,
                                                  const float* __restrict__ bias,
                                                  float* __restrict__ y) {
  const int tid = threadIdx.x;
  const int b0  = blockIdx.x * 8;
  const float* zb = z + (size_t)b0 * 128;

  const int c0 = tid, c1 = tid + 256, c2 = tid + 512, c3 = tid + 768;
  const bool v3 = (c3 < 784);

  float acc0[8], acc1[8], acc2[8], acc3[8];
  {
    float bv0 = bias[c0], bv1 = bias[c1], bv2 = bias[c2];
    float bv3 = v3 ? bias[c3] : 0.f;
#pragma unroll
    for (int i = 0; i < 8; i++) { acc0[i] = bv0; acc1[i] = bv1; acc2[i] = bv2; acc3[i] = bv3; }
  }

  for (int k0 = 0; k0 < 128; k0 += 4) {
    float4 zq[8];
#pragma unroll
    for (int i = 0; i < 8; i++) zq[i] = *(const float4*)&zb[i * 128 + k0];
#pragma unroll
    for (int j = 0; j < 4; j++) {
      const float* Wr = &W[(size_t)(k0 + j) * 784];
      float w0 = Wr[c0], w1 = Wr[c1], w2 = Wr[c2];
      float w3 = v3 ? Wr[c3] : 0.f;
#pragma unroll
      for (int i = 0; i < 8; i++) {
        float zv = (j == 0) ? zq[i].x : (j == 1) ? zq[i].y : (j == 2) ? zq[i].z : zq[i].w;
        acc0[i] = fmaf(zv, w0, acc0[i]);
        acc1[i] = fmaf(zv, w1, acc1[i]);
        acc2[i] = fmaf(zv, w2, acc2[i]);
        acc3[i] = fmaf(zv, w3, acc3[i]);
      }
    }
  }

#pragma unroll
  for (int i = 0; i < 8; i++) {
    size_t row = (size_t)(b0 + i) * 784;
    y[row + c0] = fast_rcp(1.f + fast_exp2(-acc0[i] * LOG2E));
    y[row + c1] = fast_rcp(1.f + fast_exp2(-acc1[i] * LOG2E));
    y[row + c2] = fast_rcp(1.f + fast_exp2(-acc2[i] * LOG2E));
    if (v3) y[row + c3] = fast_rcp(1.f + fast_exp2(-acc3[i] * LOG2E));
  }
}

// ---------------------------------------------------------------------------
extern "C" void kernel_launch(void* const* d_in, const int* in_sizes, int n_in,
                              void* d_out, int out_size, void* d_ws, size_t ws_size,
                              hipStream_t stream) {
  const float* x     = (const float*)d_in[0];
  const float* u     = (const float*)d_in[1];
  const float* W_enc = (const float*)d_in[2];
  const float* b_enc = (const float*)d_in[3];
  const float* W_dec = (const float*)d_in[4];
  const float* b_dec = (const float*)d_in[5];
  const float* prior = (const float*)d_in[6];

  float* out = (float*)d_out;
  float* du  = out;                       // [4096,128]
  float* zz  = out + 4096 * 128;          // [4096,128]
  float* y   = out + 2 * 4096 * 128;      // [4096,784]

  enc_kernel <<<256, 256, 0, stream>>>(x, W_enc, b_enc, du);
  race_kernel<<<512, 256, 0, stream>>>(u, du, prior, zz);
  dec_kernel <<<512, 256, 0, stream>>>(zz, W_dec, b_dec, y);
}

// Round 5
// 784.840 us; speedup vs baseline: 1.0993x; 1.0993x over previous
//
#include <hip/hip_runtime.h>
#include <cstdint>
#include <cstddef>

#define LOG2E 1.44269504088896340736f
#define LN2   0.69314718055994530942f

// Fast transcendental wrappers -> single gfx950 instructions.
__device__ __forceinline__ float fast_log2(float x) { return __builtin_amdgcn_logf(x); }   // v_log_f32
__device__ __forceinline__ float fast_exp2(float x) { return __builtin_amdgcn_exp2f(x); }  // v_exp_f32
__device__ __forceinline__ float fast_rcp(float x)  { return __builtin_amdgcn_rcpf(x); }   // v_rcp_f32

// B=4096, D_IN=784, D_Z=128, N_TRIALS=256, T_TEMP=1.0

// ---------------------------------------------------------------------------
// K1: encoder GEMM  du = min(x @ W_enc + b_enc, 5)   (unchanged from R0)
// ---------------------------------------------------------------------------
__global__ __launch_bounds__(256) void enc_kernel(const float* __restrict__ x,
                                                  const float* __restrict__ W,
                                                  const float* __restrict__ bias,
                                                  float* __restrict__ du) {
  __shared__ float xs[16][16];
  __shared__ float ws[16][128];
  const int tid  = threadIdx.x;
  const int row0 = blockIdx.x * 16;
  const int cg   = tid & 31;
  const int rg   = tid >> 5;

  float4 a0 = {0.f, 0.f, 0.f, 0.f};
  float4 a1 = {0.f, 0.f, 0.f, 0.f};

  for (int k0 = 0; k0 < 784; k0 += 16) {
    __syncthreads();
    if (tid < 64) {
      int r = tid >> 2, kc = (tid & 3) * 4;
      *(float4*)&xs[r][kc] = *(const float4*)&x[(size_t)(row0 + r) * 784 + k0 + kc];
    }
#pragma unroll
    for (int j = 0; j < 2; j++) {
      int i = tid + 256 * j;
      int k = i >> 5, c4 = (i & 31) * 4;
      *(float4*)&ws[k][c4] = *(const float4*)&W[(size_t)(k0 + k) * 128 + c4];
    }
    __syncthreads();
#pragma unroll
    for (int k = 0; k < 16; k++) {
      float x0 = xs[rg * 2][k];
      float x1 = xs[rg * 2 + 1][k];
      float4 w = *(const float4*)&ws[k][cg * 4];
      a0.x = fmaf(x0, w.x, a0.x); a0.y = fmaf(x0, w.y, a0.y);
      a0.z = fmaf(x0, w.z, a0.z); a0.w = fmaf(x0, w.w, a0.w);
      a1.x = fmaf(x1, w.x, a1.x); a1.y = fmaf(x1, w.y, a1.y);
      a1.z = fmaf(x1, w.z, a1.z); a1.w = fmaf(x1, w.w, a1.w);
    }
  }

  float4 bb = *(const float4*)&bias[cg * 4];
  float4 r0, r1;
  r0.x = fminf(a0.x + bb.x, 5.f); r0.y = fminf(a0.y + bb.y, 5.f);
  r0.z = fminf(a0.z + bb.z, 5.f); r0.w = fminf(a0.w + bb.w, 5.f);
  r1.x = fminf(a1.x + bb.x, 5.f); r1.y = fminf(a1.y + bb.y, 5.f);
  r1.z = fminf(a1.z + bb.z, 5.f); r1.w = fminf(a1.w + bb.w, 5.f);
  *(float4*)&du[(size_t)(row0 + rg * 2)     * 128 + cg * 4] = r0;
  *(float4*)&du[(size_t)(row0 + rg * 2 + 1) * 128 + cg * 4] = r1;
}

// ---------------------------------------------------------------------------
// K2: exponential race v3 = R0 layout + 4 trials/iteration.
//   R0 consumed each float4 right after issue: with 8 waves/CU the
//   compute-per-latency was 8*96~768 cyc < ~900 cyc HBM latency ->
//   latency-bound. 4 loads in flight per iter doubles MLP (8*192~1536 cyc)
//   and halves loop/ballot overhead. Early-exit check every 4 trials
//   (was 2): only ADDS terms the exact sum contains -> error <= v1's.
// ---------------------------------------------------------------------------
__global__ __launch_bounds__(256) void race_kernel(const float* __restrict__ u,
                                                   const float* __restrict__ du,
                                                   const float* __restrict__ prior,
                                                   float* __restrict__ zout) {
  const int g  = blockIdx.x * 256 + threadIdx.x;  // 0..131071
  const int b  = g >> 5;                          // batch row (32 threads/row)
  const int z4 = (g & 31) * 4;                    // z-quad start

  const float4 d = *(const float4*)&du[(size_t)b * 128 + z4];
  const float4 p = *(const float4*)&prior[z4];

  float sinv[4];
  {
    const float dd[4] = {d.x, d.y, d.z, d.w};
    const float pp[4] = {p.x, p.y, p.z, p.w};
#pragma unroll
    for (int j = 0; j < 4; j++) {
      float lr   = fminf(dd[j] + fminf(pp[j], 5.f), 5.f);
      float rate = fast_exp2(lr * LOG2E) + 1e-6f;   // e^lr
      sinv[j]    = -LN2 / rate;                     // folds ln2 and 1/rate
    }
  }

  float t[4]   = {0.f, 0.f, 0.f, 0.f};
  float acc[4] = {0.f, 0.f, 0.f, 0.f};
  const float* up = u + (size_t)b * 128 + z4;
  const float TMAX = 18.f;
  const size_t STRIDE = (size_t)4096 * 128;

  for (int tt = 0; tt < 256; tt += 4) {
    // monotone: once all 4 chains pass TMAX this lane is done forever
    bool act = fminf(fminf(t[0], t[1]), fminf(t[2], t[3])) < TMAX;
    if (!__any(act)) break;          // wave-uniform exit
    if (act) {
      // issue all 4 trial loads before first use: 4 VMEM in flight
      float4 ua = *(const float4*)&up[(size_t)tt * STRIDE];
      float4 ub = *(const float4*)&up[(size_t)(tt + 1) * STRIDE];
      float4 uc = *(const float4*)&up[(size_t)(tt + 2) * STRIDE];
      float4 ud = *(const float4*)&up[(size_t)(tt + 3) * STRIDE];
      const float uaj[4] = {ua.x, ua.y, ua.z, ua.w};
      const float ubj[4] = {ub.x, ub.y, ub.z, ub.w};
      const float ucj[4] = {uc.x, uc.y, uc.z, uc.w};
      const float udj[4] = {ud.x, ud.y, ud.z, ud.w};
#pragma unroll
      for (int j = 0; j < 4; j++) {
        float l = fast_log2(1.f - uaj[j]);          // -log1p(-u) = -ln2*log2(1-u)
        t[j] = fmaf(l, sinv[j], t[j]);
        float e = fast_exp2(fmaf(t[j], LOG2E, -LOG2E));
        acc[j] += fast_rcp(1.f + e);                // sigmoid(1 - times)
        l = fast_log2(1.f - ubj[j]);
        t[j] = fmaf(l, sinv[j], t[j]);
        e = fast_exp2(fmaf(t[j], LOG2E, -LOG2E));
        acc[j] += fast_rcp(1.f + e);
        l = fast_log2(1.f - ucj[j]);
        t[j] = fmaf(l, sinv[j], t[j]);
        e = fast_exp2(fmaf(t[j], LOG2E, -LOG2E));
        acc[j] += fast_rcp(1.f + e);
        l = fast_log2(1.f - udj[j]);
        t[j] = fmaf(l, sinv[j], t[j]);
        e = fast_exp2(fmaf(t[j], LOG2E, -LOG2E));
        acc[j] += fast_rcp(1.f + e);
      }
    }
  }

  float4 r; r.x = acc[0]; r.y = acc[1]; r.z = acc[2]; r.w = acc[3];
  *(float4*)&zout[(size_t)b * 128 + z4] = r;
}

// ---------------------------------------------------------------------------
// K3: decoder  y = sigmoid(z @ W_dec + b_dec)  — reverted to v1 (R0).
//   R1/R2 isolated dec v2 (no-LDS, register-blocked) as a +75 us regressor:
//   block-uniform global z reads did NOT scalarize; LDS broadcast reads
//   here cost only ~8 us. Keep the LDS version.
// ---------------------------------------------------------------------------
__global__ __launch_bounds__(256) void dec_kernel(const float* __restrict__ z,
                                                  const float* __restrict__ W,
                                                  const float* __restrict__ bias,
                                                  float* __restrict__ y) {
  __shared__ float zs[8 * 128];
  const int tid = threadIdx.x;
  const int b0  = blockIdx.x * 8;
  *(float4*)&zs[tid * 4] = *(const float4*)&z[(size_t)b0 * 128 + tid * 4];
  __syncthreads();

  for (int col = tid; col < 784; col += 256) {
    float bv = bias[col];
    float acc[8];
#pragma unroll
    for (int i = 0; i < 8; i++) acc[i] = bv;
#pragma unroll 4
    for (int k = 0; k < 128; k++) {
      float w = W[(size_t)k * 784 + col];
#pragma unroll
      for (int i = 0; i < 8; i++) acc[i] = fmaf(zs[i * 128 + k], w, acc[i]);
    }
#pragma unroll
    for (int i = 0; i < 8; i++) {
      float ex = fast_exp2(-acc[i] * LOG2E);
      y[(size_t)(b0 + i) * 784 + col] = fast_rcp(1.f + ex);
    }
  }
}

// ---------------------------------------------------------------------------
extern "C" void kernel_launch(void* const* d_in, const int* in_sizes, int n_in,
                              void* d_out, int out_size, void* d_ws, size_t ws_size,
                              hipStream_t stream) {
  const float* x     = (const float*)d_in[0];
  const float* u     = (const float*)d_in[1];
  const float* W_enc = (const float*)d_in[2];
  const float* b_enc = (const float*)d_in[3];
  const float* W_dec = (const float*)d_in[4];
  const float* b_dec = (const float*)d_in[5];
  const float* prior = (const float*)d_in[6];

  float* out = (float*)d_out;
  float* du  = out;                       // [4096,128]
  float* zz  = out + 4096 * 128;          // [4096,128]
  float* y   = out + 2 * 4096 * 128;      // [4096,784]

  enc_kernel <<<256, 256, 0, stream>>>(x, W_enc, b_enc, du);
  race_kernel<<<512, 256, 0, stream>>>(u, du, prior, zz);
  dec_kernel <<<512, 256, 0, stream>>>(zz, W_dec, b_dec, y);
}